// Round 1
// baseline (119.979 us; speedup 1.0000x reference)
//
#include <hip/hip_runtime.h>
#include <math.h>

#define W_ 128
#define H_ 96
#define C_ 128
#define NB_ 2
#define HW_ (H_ * W_)          // 12288
#define K_ 81
#define FLOW_ELEMS (NB_ * 2 * H_ * W_)   // 49152

// Kernel 1: raw (unscaled) local correlation.
// Block = 256 threads = 4 waves. Each block owns an 8x8 pixel tile of one batch.
// Wave w accumulates channels [32w, 32w+32); block reduces via LDS atomics.
// Output: corr[b][y*W+x][k] written into the match_prob region of d_out.
__global__ __launch_bounds__(256) void corr_kernel(const float* __restrict__ f0,
                                                   const float* __restrict__ f1,
                                                   float* __restrict__ corr) {
    // wbuf row stride 20 floats: 16B-aligned rows, <=2-way bank aliasing (free)
    __shared__ float wbuf[4][4][16][20];
    __shared__ float accbuf[64][K_];

    const int t = threadIdx.x;
    const int wave = t >> 6;
    const int lane = t & 63;
    const int blk = blockIdx.x;
    const int bx = (blk & 15) << 3;          // 16 tiles in x
    const int by = ((blk >> 4) % 12) << 3;   // 12 tiles in y
    const int b  = blk / 192;                // batch
    const int tx = lane & 7, ty = lane >> 3; // pixel within tile

    // zero the block accumulator
    for (int i = t; i < 64 * K_; i += 256) (&accbuf[0][0])[i] = 0.f;
    __syncthreads();

    float acc[K_];
#pragma unroll
    for (int k = 0; k < K_; ++k) acc[k] = 0.f;

    const float* f0b = f0 + (size_t)b * C_ * HW_;
    const float* f1b = f1 + (size_t)b * C_ * HW_;
    const int c0 = wave * 32;

    // staging slot: 16 rows x 4 float4-vectors per channel
    const int srow = lane >> 2, svec = lane & 3;
    const int gy_s = by + srow - 4;
    const int gx_s = bx + (svec << 2) - 4;   // multiple of 4; never partially OOB
    const bool ok = (gy_s >= 0) && (gy_s < H_) && (gx_s >= 0) && (gx_s < W_);
    const int f0off = (by + ty) * W_ + (bx + tx);

    for (int chunk = 0; chunk < 8; ++chunk) {
        const int cbase = c0 + chunk * 4;
#pragma unroll
        for (int ch = 0; ch < 4; ++ch) {
            float4 v = make_float4(0.f, 0.f, 0.f, 0.f);
            if (ok) v = *(const float4*)(f1b + (size_t)(cbase + ch) * HW_ + gy_s * W_ + gx_s);
            *(float4*)&wbuf[wave][ch][srow][svec << 2] = v;
        }
        // per-wave private buffer: no __syncthreads needed; same-wave DS order holds
#pragma unroll
        for (int ch = 0; ch < 4; ++ch) {
            const float f0v = f0b[(size_t)(cbase + ch) * HW_ + f0off];
#pragma unroll
            for (int dy = 0; dy < 9; ++dy)
#pragma unroll
                for (int dx = 0; dx < 9; ++dx)
                    acc[dy * 9 + dx] += f0v * wbuf[wave][ch][ty + dy][tx + dx];
        }
    }

    // block-level channel reduction
#pragma unroll
    for (int k = 0; k < K_; ++k) atomicAdd(&accbuf[lane][k], acc[k]);
    __syncthreads();

    // coalesced-ish writeout of raw corr
    float* cb = corr + (size_t)b * HW_ * K_;
    for (int i = t; i < 64 * K_; i += 256) {
        const int pl = i / K_;
        const int k  = i - pl * K_;
        const int gy = by + (pl >> 3);
        const int gx = bx + (pl & 7);
        cb[(size_t)(gy * W_ + gx) * K_ + k] = accbuf[pl][k];
    }
}

// Kernel 2: scale by 1/sqrt(C), softmax over K in-place, and flow.
// Wave per pixel; lane handles k=lane and k=lane+64 (valid for lane<17).
__global__ __launch_bounds__(256) void softmax_kernel(float* __restrict__ out) {
    const int t = threadIdx.x;
    const int wave = t >> 6, lane = t & 63;
    const int px = (blockIdx.x << 2) + wave;      // 0 .. 24575
    const int b = px / HW_;
    const int pl = px - b * HW_;
    const int y = pl >> 7, x = pl & 127;

    float* corr = out + FLOW_ELEMS + (size_t)px * K_;
    const float scale = 0.08838834764831845f;     // 1/sqrt(128)

    const bool has1 = lane < (K_ - 64);           // lane < 17
    float v0 = corr[lane] * scale;
    float v1 = has1 ? corr[lane + 64] * scale : -1e30f;

    float m = fmaxf(v0, v1);
#pragma unroll
    for (int off = 32; off; off >>= 1) m = fmaxf(m, __shfl_xor(m, off));

    float e0 = __expf(v0 - m);
    float e1 = has1 ? __expf(v1 - m) : 0.f;
    float s = e0 + e1;
#pragma unroll
    for (int off = 32; off; off >>= 1) s += __shfl_xor(s, off);

    const float inv = 1.f / s;
    const float p0 = e0 * inv;
    const float p1 = e1 * inv;

    corr[lane] = p0;
    if (has1) corr[lane + 64] = p1;

    float fx = p0 * (float)(lane % 9 - 4) + p1 * (float)((lane + 64) % 9 - 4);
    float fy = p0 * (float)(lane / 9 - 4) + p1 * (float)((lane + 64) / 9 - 4);
#pragma unroll
    for (int off = 32; off; off >>= 1) {
        fx += __shfl_xor(fx, off);
        fy += __shfl_xor(fy, off);
    }

    if (lane == 0) {
        out[((size_t)(b * 2 + 0) * H_ + y) * W_ + x] = fx;
        out[((size_t)(b * 2 + 1) * H_ + y) * W_ + x] = fy;
    }
}

extern "C" void kernel_launch(void* const* d_in, const int* in_sizes, int n_in,
                              void* d_out, int out_size, void* d_ws, size_t ws_size,
                              hipStream_t stream) {
    (void)in_sizes; (void)n_in; (void)d_ws; (void)ws_size; (void)out_size;
    const float* f0 = (const float*)d_in[0];
    const float* f1 = (const float*)d_in[1];
    float* out = (float*)d_out;

    // Kernel 1: 16 x-tiles * 12 y-tiles * 2 batches = 384 blocks
    corr_kernel<<<384, 256, 0, stream>>>(f0, f1, out + FLOW_ELEMS);
    // Kernel 2: 24576 pixels / 4 waves per block
    softmax_kernel<<<6144, 256, 0, stream>>>(out);
}

// Round 2
// 93.777 us; speedup vs baseline: 1.2794x; 1.2794x over previous
//
#include <hip/hip_runtime.h>
#include <math.h>

#define W_ 128
#define H_ 96
#define C_ 128
#define NB_ 2
#define HW_ (H_ * W_)          // 12288
#define K_ 81
#define FLOW_ELEMS (NB_ * 2 * H_ * W_)   // 49152
#define HALO_W 136             // cols -4..131
#define HALO_H 9               // dy -4..4
#define CHUNK 8                // channels staged per iter (2 per c-group)
#define NITER 16               // 128 / CHUNK * ... (2 ch per cgroup per iter, 32 ch/cgroup)
#define NSLOT 2448             // CHUNK * HALO_H * 34 quads
#define ACC_STRIDE 83          // padded K stride (bank-spread for atomics)

// Block = 768 threads = 12 waves = 4 cgroups (32 ch each) x 3 dygroups (3 dy rows each).
// Tile = one full image row (128 px); lane owns pixels x=2*lane, 2*lane+1.
// Grid = 96 rows * 2 batches = 192 blocks.
__global__ __launch_bounds__(768, 3) void corr_kernel(const float* __restrict__ f0,
                                                      const float* __restrict__ f1,
                                                      float* __restrict__ corr) {
    __shared__ float buf[2][CHUNK][HALO_H][HALO_W];   // 78336 B
    __shared__ float accbuf[W_][ACC_STRIDE];          // 42496 B

    const int t = threadIdx.x;
    const int wave = t >> 6;
    const int lane = t & 63;             // rx: pixel pair base x = 2*lane
    const int cg = wave & 3;             // channel group
    const int dg = wave >> 2;            // dy group: dy rows dg*3 .. dg*3+2
    const int y0 = blockIdx.x % H_;
    const int b  = blockIdx.x / H_;

    // ---- staging slot precompute (4 slots per thread; ids iter-invariant) ----
    int s_ch[4], s_row[4], s_q[4];
    bool s_live[4];
    int s_lds[4];
#pragma unroll
    for (int i = 0; i < 4; ++i) {
        const int s = t + i * 768;
        s_live[i] = (s < NSLOT);
        const int s2 = s_live[i] ? s : 0;
        s_ch[i] = s2 / (HALO_H * 34);
        const int rem = s2 - s_ch[i] * (HALO_H * 34);
        s_row[i] = rem / 34;
        s_q[i] = rem - s_row[i] * 34;
        s_lds[i] = (s_ch[i] * HALO_H + s_row[i]) * HALO_W + s_q[i] * 4;
    }

    // zero block accumulator
    for (int i = t; i < W_ * ACC_STRIDE; i += 768) (&accbuf[0][0])[i] = 0.f;

    float acc0[27], acc1[27];
#pragma unroll
    for (int k = 0; k < 27; ++k) { acc0[k] = 0.f; acc1[k] = 0.f; }

    const float* f1b = f1 + (size_t)b * C_ * HW_;
    const float* f0b = f0 + (size_t)b * C_ * HW_;

    // ---- prologue: stage chunk 0 into buf[0] ----
#pragma unroll
    for (int i = 0; i < 4; ++i) {
        if (s_live[i]) {
            const int c = (s_ch[i] >> 1) * 32 + (s_ch[i] & 1);   // nit = 0
            const int gy = y0 + s_row[i] - 4;
            const int q = s_q[i];
            float4 v = make_float4(0.f, 0.f, 0.f, 0.f);
            if (gy >= 0 && gy < H_ && q >= 1 && q <= 32)
                v = *(const float4*)(f1b + (size_t)c * HW_ + gy * W_ + (q * 4 - 4));
            *(float4*)(&buf[0][0][0][0] + s_lds[i]) = v;
        }
    }
    __syncthreads();

    // ---- main loop over 16 chunks (2 channels per cgroup each) ----
    for (int it = 0; it < NITER; ++it) {
        const int p = it & 1;
        const bool do_stage = (it + 1 < NITER);

        // T14 async split: issue next-chunk global loads now, write LDS after compute
        float4 vals[4];
        if (do_stage) {
            const int nit = it + 1;
#pragma unroll
            for (int i = 0; i < 4; ++i) {
                float4 v = make_float4(0.f, 0.f, 0.f, 0.f);
                if (s_live[i]) {
                    const int c = (s_ch[i] >> 1) * 32 + nit * 2 + (s_ch[i] & 1);
                    const int gy = y0 + s_row[i] - 4;
                    const int q = s_q[i];
                    if (gy >= 0 && gy < H_ && q >= 1 && q <= 32)
                        v = *(const float4*)(f1b + (size_t)c * HW_ + gy * W_ + (q * 4 - 4));
                }
                vals[i] = v;
            }
        }

        // compute this chunk: channels cg*32 + it*2 + {0,1}
#pragma unroll
        for (int sub = 0; sub < 2; ++sub) {
            const int c = cg * 32 + it * 2 + sub;
            const float2 f0v = *(const float2*)(f0b + (size_t)c * HW_ + y0 * W_ + 2 * lane);
            const int ch8 = cg * 2 + sub;
#pragma unroll
            for (int dl = 0; dl < 3; ++dl) {
                const int hr = dg * 3 + dl;
                const float2* row = (const float2*)(&buf[p][ch8][hr][0]) + lane;
                const float2 w0 = row[0], w1 = row[1], w2 = row[2], w3 = row[3], w4 = row[4];
                const float v[10] = {w0.x, w0.y, w1.x, w1.y, w2.x,
                                     w2.y, w3.x, w3.y, w4.x, w4.y};
#pragma unroll
                for (int dx = 0; dx < 9; ++dx) {
                    acc0[dl * 9 + dx] += f0v.x * v[dx];
                    acc1[dl * 9 + dx] += f0v.y * v[dx + 1];
                }
            }
        }

        if (do_stage) {
#pragma unroll
            for (int i = 0; i < 4; ++i)
                if (s_live[i]) *(float4*)(&buf[p ^ 1][0][0][0] + s_lds[i]) = vals[i];
        }
        __syncthreads();
    }

    // ---- cgroup reduction via LDS atomics (4-way per address) ----
#pragma unroll
    for (int dl = 0; dl < 3; ++dl)
#pragma unroll
        for (int dx = 0; dx < 9; ++dx) {
            const int k = (dg * 3 + dl) * 9 + dx;
            atomicAdd(&accbuf[2 * lane][k], acc0[dl * 9 + dx]);
            atomicAdd(&accbuf[2 * lane + 1][k], acc1[dl * 9 + dx]);
        }
    __syncthreads();

    // ---- coalesced writeout: flat global idx i == px*81 + k ----
    float* cb = corr + ((size_t)b * HW_ + (size_t)y0 * W_) * K_;
    for (int i = t; i < W_ * K_; i += 768) {
        const int px = i / K_;
        const int k = i - px * K_;
        cb[i] = accbuf[px][k];
    }
}

// Kernel 2: scale by 1/sqrt(C), softmax over K in-place, and flow.
__global__ __launch_bounds__(256) void softmax_kernel(float* __restrict__ out) {
    const int t = threadIdx.x;
    const int wave = t >> 6, lane = t & 63;
    const int px = (blockIdx.x << 2) + wave;      // 0 .. 24575
    const int b = px / HW_;
    const int pl = px - b * HW_;
    const int y = pl >> 7, x = pl & 127;

    float* corr = out + FLOW_ELEMS + (size_t)px * K_;
    const float scale = 0.08838834764831845f;     // 1/sqrt(128)

    const bool has1 = lane < (K_ - 64);           // lane < 17
    float v0 = corr[lane] * scale;
    float v1 = has1 ? corr[lane + 64] * scale : -1e30f;

    float m = fmaxf(v0, v1);
#pragma unroll
    for (int off = 32; off; off >>= 1) m = fmaxf(m, __shfl_xor(m, off));

    float e0 = __expf(v0 - m);
    float e1 = has1 ? __expf(v1 - m) : 0.f;
    float s = e0 + e1;
#pragma unroll
    for (int off = 32; off; off >>= 1) s += __shfl_xor(s, off);

    const float inv = 1.f / s;
    const float p0 = e0 * inv;
    const float p1 = e1 * inv;

    corr[lane] = p0;
    if (has1) corr[lane + 64] = p1;

    float fx = p0 * (float)(lane % 9 - 4) + p1 * (float)((lane + 64) % 9 - 4);
    float fy = p0 * (float)(lane / 9 - 4) + p1 * (float)((lane + 64) / 9 - 4);
#pragma unroll
    for (int off = 32; off; off >>= 1) {
        fx += __shfl_xor(fx, off);
        fy += __shfl_xor(fy, off);
    }

    if (lane == 0) {
        out[((size_t)(b * 2 + 0) * H_ + y) * W_ + x] = fx;
        out[((size_t)(b * 2 + 1) * H_ + y) * W_ + x] = fy;
    }
}

extern "C" void kernel_launch(void* const* d_in, const int* in_sizes, int n_in,
                              void* d_out, int out_size, void* d_ws, size_t ws_size,
                              hipStream_t stream) {
    (void)in_sizes; (void)n_in; (void)d_ws; (void)ws_size; (void)out_size;
    const float* f0 = (const float*)d_in[0];
    const float* f1 = (const float*)d_in[1];
    float* out = (float*)d_out;

    corr_kernel<<<192, 768, 0, stream>>>(f0, f1, out + FLOW_ELEMS);
    softmax_kernel<<<6144, 256, 0, stream>>>(out);
}